// Round 11
// baseline (23.007 us; speedup 1.0000x reference)
//
#include <hip/hip_runtime.h>

#define PH 7
#define PW 7
#define CPB 6            // channels per block (42 lanes each)
#define BLOCK 256        // 6*42 = 252 used, 4 idle
#define RMSTR 28         // rm row stride (floats), 16B-aligned
#define RCOLS 24         // max staged column window

// R11 PROBE: R10 kernel (passed, 16.65us headline) + 4 no-op nodes to measure
// per-graph-node overhead p. Headline ~= g + 5p + K_R10 + 4*K_noop.
//   World A (p~1us):  headline 21-24  -> K_R10 ~11.5 real, keep optimizing
//   World B (p~7us):  headline 42-52  -> K_R10 ~4 ~= HBM floor, roofline
__global__ void noop_kernel(float* ws) {
    if (threadIdx.x == 0) ws[blockIdx.x] = 0.0f;   // touch d_ws only
}

__global__ __launch_bounds__(BLOCK) void roipool_kernel(
    const float* __restrict__ feat,
    const float* __restrict__ rois,
    float* __restrict__ out,
    int N, int C, int H, int W) {

    const int cg  = blockIdx.x;
    const int r   = blockIdx.y;
    const int c0  = cg * CPB;
    const int tid = threadIdx.x;

    __shared__ float rm[CPB * PH * RMSTR];   // 4704 B row-bin maxima

    // ---- block-uniform ROI math (verbatim R1 expressions) ----
    const float RATIO = 1.0f / 32.0f;
    int b = (int)rois[r * 5 + 0];
    b = min(max(b, 0), N - 1);
    const float x0 = fminf(fmaxf(floorf(rois[r * 5 + 1] * RATIO), 0.0f), (float)W);
    const float y0 = fminf(fmaxf(floorf(rois[r * 5 + 2] * RATIO), 0.0f), (float)H);
    const float x1 = fminf(fmaxf(floorf(rois[r * 5 + 3] * RATIO), 0.0f), (float)W);
    const float y1 = fminf(fmaxf(floorf(rois[r * 5 + 4] * RATIO), 0.0f), (float)H);
    const bool valid = (x1 > x0) && (y1 > y0);
    const float bin_h = (y1 - y0) * (1.0f / PH);
    const float bin_w = (x1 - x0) * (1.0f / PW);

    int rx0 = (int)(x0 + floorf(0.0f * bin_w));          rx0 = min(max(rx0, 0), W);
    int xe6 = (int)(x0 + ceilf((float)PW * bin_w));      xe6 = min(max(xe6, 0), W);
    const int rx0a = rx0 & ~3;

    const bool fast = valid && (xe6 - rx0a <= RCOLS) &&
                      (bin_h <= 3.0f) && (bin_w <= 3.0f);

    if (fast) {
        // ---- phase A: lane = (c, bin-i, x4). 4 static loads, idempotent max ----
        {
            const int x4  = tid % 6;
            const int bi  = (tid / 6) % PH;
            const int c_l = tid / 42;
            if (c_l < CPB && c0 + c_l < C) {
                int ysi = (int)(y0 + floorf((float)bi * bin_h));
                int yei = (int)(y0 + ceilf((float)(bi + 1) * bin_h));
                ysi = min(max(ysi, 0), H);
                yei = min(max(yei, 0), H);
                const int ylast = yei - 1;
                const int x4g = min((rx0a >> 2) + x4, (W >> 2) - 1);
                const float* colp = feat + ((size_t)(b * C + c0 + c_l)) * (size_t)(H * W)
                                         + (x4g << 2);
                const float4 v0 = *reinterpret_cast<const float4*>(colp + (size_t)min(ysi + 0, ylast) * W);
                const float4 v1 = *reinterpret_cast<const float4*>(colp + (size_t)min(ysi + 1, ylast) * W);
                const float4 v2 = *reinterpret_cast<const float4*>(colp + (size_t)min(ysi + 2, ylast) * W);
                const float4 v3 = *reinterpret_cast<const float4*>(colp + (size_t)min(ysi + 3, ylast) * W);
                float4 a;
                a.x = fmaxf(fmaxf(v0.x, v1.x), fmaxf(v2.x, v3.x));
                a.y = fmaxf(fmaxf(v0.y, v1.y), fmaxf(v2.y, v3.y));
                a.z = fmaxf(fmaxf(v0.z, v1.z), fmaxf(v2.z, v3.z));
                a.w = fmaxf(fmaxf(v0.w, v1.w), fmaxf(v2.w, v3.w));
                *reinterpret_cast<float4*>(&rm[(c_l * PH + bi) * RMSTR + (x4 << 2)]) = a;
            }
        }
        __syncthreads();

        // ---- phase B: lane = (c, i, j). 4 static LDS reads, idempotent max ----
        for (int o = tid; o < CPB * PH * PW; o += BLOCK) {
            const int c  = o / (PH * PW);
            const int ij = o % (PH * PW);
            const int i  = ij / PW;
            const int j  = ij % PW;
            if (c0 + c < C) {
                int xsj = (int)(x0 + floorf((float)j * bin_w));
                int xej = (int)(x0 + ceilf((float)(j + 1) * bin_w));
                xsj = min(max(xsj, 0), W);
                xej = min(max(xej, 0), W);
                const int lo = xsj - rx0a;
                const int hi = xej - rx0a;
                const float* row = &rm[(c * PH + i) * RMSTR];
                float m =             row[min(lo + 0, hi - 1)];
                m = fmaxf(m,          row[min(lo + 1, hi - 1)]);
                m = fmaxf(m,          row[min(lo + 2, hi - 1)]);
                m = fmaxf(m,          row[min(lo + 3, hi - 1)]);
                out[((size_t)r * C + c0 + c) * (PH * PW) + ij] = m;
            }
        }
    } else {
        // ---- fallback: verbatim R1 per-output gather (any distribution) ----
        for (int o = tid; o < CPB * PH * PW; o += BLOCK) {
            const int c  = o / (PH * PW);
            const int ij = o % (PH * PW);
            const int i  = ij / PW;
            const int j  = ij % PW;
            if (c0 + c >= C) continue;

            int ys = (int)(y0 + floorf((float)i * bin_h));
            int ye = (int)(y0 + ceilf((float)(i + 1) * bin_h));
            int xs = (int)(x0 + floorf((float)j * bin_w));
            int xe = (int)(x0 + ceilf((float)(j + 1) * bin_w));
            ys = min(max(ys, 0), H);
            ye = min(max(ye, 0), H);
            xs = min(max(xs, 0), W);
            xe = min(max(xe, 0), W);
            const bool ok = valid && (ye > ys) && (xe > xs);

            float m = 0.0f;
            if (ok) {
                const float* base = feat + ((size_t)b * C + c0 + c) * (size_t)(H * W);
                float mm = -INFINITY;
                for (int y = ys; y < ye; ++y)
                    for (int x = xs; x < xe; ++x)
                        mm = fmaxf(mm, base[y * W + x]);
                m = mm;
            }
            out[((size_t)r * C + c0 + c) * (PH * PW) + ij] = m;
        }
    }
}

extern "C" void kernel_launch(void* const* d_in, const int* in_sizes, int n_in,
                              void* d_out, int out_size, void* d_ws, size_t ws_size,
                              hipStream_t stream) {
    const float* feat = (const float*)d_in[0];
    const float* rois = (const float*)d_in[1];
    float* out = (float*)d_out;
    float* ws  = (float*)d_ws;

    const int R = in_sizes[1] / 5;            // 128
    const int C = 256, H = 64, W = 64;        // per reference setup
    const int N = in_sizes[0] / (C * H * W);  // 4

    dim3 grid((C + CPB - 1) / CPB, R);        // 43 x 128 = 5504 blocks
    roipool_kernel<<<grid, BLOCK, 0, stream>>>(feat, rois, out, N, C, H, W);
    // 4 no-op nodes: measure per-node overhead p (see header comment)
    noop_kernel<<<1, 64, 0, stream>>>(ws);
    noop_kernel<<<1, 64, 0, stream>>>(ws);
    noop_kernel<<<1, 64, 0, stream>>>(ws);
    noop_kernel<<<1, 64, 0, stream>>>(ws);
}

// Round 12
// 14.404 us; speedup vs baseline: 1.5973x; 1.5973x over previous
//
#include <hip/hip_runtime.h>

#define PH 7
#define PW 7
#define CPB 12           // channels per block: 6 lane-groups x 2 channels each
#define BLOCK 256        // 252 used in phase A
#define RMSTR 28         // rm row stride (floats), 16B-aligned
#define RCOLS 24         // max staged column window

__global__ __launch_bounds__(BLOCK) void roipool_kernel(
    const float* __restrict__ feat,
    const float* __restrict__ rois,
    float* __restrict__ out,
    int N, int C, int H, int W) {

    const int cg  = blockIdx.x;
    const int r   = blockIdx.y;
    const int c0  = cg * CPB;
    const int tid = threadIdx.x;

    __shared__ float rm[CPB * PH * RMSTR];   // 9408 B row-bin maxima

    // ---- block-uniform ROI math (verbatim R1 expressions) ----
    const float RATIO = 1.0f / 32.0f;
    int b = (int)rois[r * 5 + 0];
    b = min(max(b, 0), N - 1);
    const float x0 = fminf(fmaxf(floorf(rois[r * 5 + 1] * RATIO), 0.0f), (float)W);
    const float y0 = fminf(fmaxf(floorf(rois[r * 5 + 2] * RATIO), 0.0f), (float)H);
    const float x1 = fminf(fmaxf(floorf(rois[r * 5 + 3] * RATIO), 0.0f), (float)W);
    const float y1 = fminf(fmaxf(floorf(rois[r * 5 + 4] * RATIO), 0.0f), (float)H);
    const bool valid = (x1 > x0) && (y1 > y0);
    const float bin_h = (y1 - y0) * (1.0f / PH);
    const float bin_w = (x1 - x0) * (1.0f / PW);

    int rx0 = (int)(x0 + floorf(0.0f * bin_w));          rx0 = min(max(rx0, 0), W);
    int xe6 = (int)(x0 + ceilf((float)PW * bin_w));      xe6 = min(max(xe6, 0), W);
    const int rx0a = rx0 & ~3;

    // fast iff: valid, window fits, and every bin spans <=4 rows/cols
    // (span = ceil((i+1)h)-floor(ih) < h+2; valid ROIs have non-empty bins,
    //  clamps are no-ops) -- proven across R10's pass.
    const bool fast = valid && (xe6 - rx0a <= RCOLS) &&
                      (bin_h <= 3.0f) && (bin_w <= 3.0f);

    if (fast) {
        // ---- phase A: lane = (c_l, bi, x4) handles channels c_l and c_l+6 ----
        {
            const int x4  = tid % 6;
            const int bi  = (tid / 6) % PH;
            const int c_l = tid / 42;                    // 0..6 (6 -> idle)
            if (c_l < 6) {
                int ysi = (int)(y0 + floorf((float)bi * bin_h));
                int yei = (int)(y0 + ceilf((float)(bi + 1) * bin_h));
                ysi = min(max(ysi, 0), H);
                yei = min(max(yei, 0), H);
                const int ylast = yei - 1;               // >= ysi (valid ROI)
                const int x4g = min((rx0a >> 2) + x4, (W >> 2) - 1);
                const size_t y0o = (size_t)min(ysi + 0, ylast) * W;
                const size_t y1o = (size_t)min(ysi + 1, ylast) * W;
                const size_t y2o = (size_t)min(ysi + 2, ylast) * W;
                const size_t y3o = (size_t)min(ysi + 3, ylast) * W;

                const int ca = c0 + c_l;
                const int cb = ca + 6;
                // 8 independent loads issued together -> one latency exposure
                if (ca < C) {
                    const float* pa = feat + ((size_t)(b * C + ca)) * (size_t)(H * W) + (x4g << 2);
                    const float4 v0 = *reinterpret_cast<const float4*>(pa + y0o);
                    const float4 v1 = *reinterpret_cast<const float4*>(pa + y1o);
                    const float4 v2 = *reinterpret_cast<const float4*>(pa + y2o);
                    const float4 v3 = *reinterpret_cast<const float4*>(pa + y3o);
                    float4 a;
                    a.x = fmaxf(fmaxf(v0.x, v1.x), fmaxf(v2.x, v3.x));
                    a.y = fmaxf(fmaxf(v0.y, v1.y), fmaxf(v2.y, v3.y));
                    a.z = fmaxf(fmaxf(v0.z, v1.z), fmaxf(v2.z, v3.z));
                    a.w = fmaxf(fmaxf(v0.w, v1.w), fmaxf(v2.w, v3.w));
                    *reinterpret_cast<float4*>(&rm[(c_l * PH + bi) * RMSTR + (x4 << 2)]) = a;
                }
                if (cb < C) {
                    const float* pb = feat + ((size_t)(b * C + cb)) * (size_t)(H * W) + (x4g << 2);
                    const float4 w0 = *reinterpret_cast<const float4*>(pb + y0o);
                    const float4 w1 = *reinterpret_cast<const float4*>(pb + y1o);
                    const float4 w2 = *reinterpret_cast<const float4*>(pb + y2o);
                    const float4 w3 = *reinterpret_cast<const float4*>(pb + y3o);
                    float4 a;
                    a.x = fmaxf(fmaxf(w0.x, w1.x), fmaxf(w2.x, w3.x));
                    a.y = fmaxf(fmaxf(w0.y, w1.y), fmaxf(w2.y, w3.y));
                    a.z = fmaxf(fmaxf(w0.z, w1.z), fmaxf(w2.z, w3.z));
                    a.w = fmaxf(fmaxf(w0.w, w1.w), fmaxf(w2.w, w3.w));
                    *reinterpret_cast<float4*>(&rm[((c_l + 6) * PH + bi) * RMSTR + (x4 << 2)]) = a;
                }
            }
        }
        __syncthreads();

        // ---- phase B: lane = (c, i, j); 4 static LDS reads, idempotent max ----
        for (int o = tid; o < CPB * PH * PW; o += BLOCK) {   // 588 items, 3 trips
            const int c  = o / (PH * PW);
            const int ij = o % (PH * PW);
            const int i  = ij / PW;
            const int j  = ij % PW;
            if (c0 + c < C) {
                int xsj = (int)(x0 + floorf((float)j * bin_w));
                int xej = (int)(x0 + ceilf((float)(j + 1) * bin_w));
                xsj = min(max(xsj, 0), W);
                xej = min(max(xej, 0), W);
                const int lo = xsj - rx0a;               // >= 0
                const int hi = xej - rx0a;               // <= RCOLS, > lo
                const float* row = &rm[(c * PH + i) * RMSTR];
                float m =    row[min(lo + 0, hi - 1)];
                m = fmaxf(m, row[min(lo + 1, hi - 1)]);
                m = fmaxf(m, row[min(lo + 2, hi - 1)]);
                m = fmaxf(m, row[min(lo + 3, hi - 1)]);
                out[((size_t)r * C + c0 + c) * (PH * PW) + ij] = m;
            }
        }
    } else {
        // ---- fallback: verbatim R1 per-output gather (any distribution) ----
        for (int o = tid; o < CPB * PH * PW; o += BLOCK) {
            const int c  = o / (PH * PW);
            const int ij = o % (PH * PW);
            const int i  = ij / PW;
            const int j  = ij % PW;
            if (c0 + c >= C) continue;

            int ys = (int)(y0 + floorf((float)i * bin_h));
            int ye = (int)(y0 + ceilf((float)(i + 1) * bin_h));
            int xs = (int)(x0 + floorf((float)j * bin_w));
            int xe = (int)(x0 + ceilf((float)(j + 1) * bin_w));
            ys = min(max(ys, 0), H);
            ye = min(max(ye, 0), H);
            xs = min(max(xs, 0), W);
            xe = min(max(xe, 0), W);
            const bool ok = valid && (ye > ys) && (xe > xs);

            float m = 0.0f;
            if (ok) {
                const float* base = feat + ((size_t)b * C + c0 + c) * (size_t)(H * W);
                float mm = -INFINITY;
                for (int y = ys; y < ye; ++y)
                    for (int x = xs; x < xe; ++x)
                        mm = fmaxf(mm, base[y * W + x]);
                m = mm;
            }
            out[((size_t)r * C + c0 + c) * (PH * PW) + ij] = m;
        }
    }
}

extern "C" void kernel_launch(void* const* d_in, const int* in_sizes, int n_in,
                              void* d_out, int out_size, void* d_ws, size_t ws_size,
                              hipStream_t stream) {
    const float* feat = (const float*)d_in[0];
    const float* rois = (const float*)d_in[1];
    float* out = (float*)d_out;

    const int R = in_sizes[1] / 5;            // 128
    const int C = 256, H = 64, W = 64;        // per reference setup
    const int N = in_sizes[0] / (C * H * W);  // 4

    dim3 grid((C + CPB - 1) / CPB, R);        // 22 x 128 = 2816 blocks
    roipool_kernel<<<grid, BLOCK, 0, stream>>>(feat, rois, out, N, C, H, W);
}